// Round 9
// baseline (594.669 us; speedup 1.0000x reference)
//
#include <hip/hip_runtime.h>
#include <math.h>

#define B_ 4
#define N_ 2048
#define D_ 256
#define H_ 8
#define L_ 4
#define DH_ 32

typedef float f32x4 __attribute__((ext_vector_type(4)));
typedef float f32x16 __attribute__((ext_vector_type(16)));
typedef short short8 __attribute__((ext_vector_type(8)));
typedef unsigned short ushort_t;
typedef ushort_t ushortx4 __attribute__((ext_vector_type(4)));
typedef ushort_t ushortx8 __attribute__((ext_vector_type(8)));

typedef __attribute__((address_space(3))) unsigned int lds_u32_t;
typedef __attribute__((address_space(1))) unsigned int glb_u32_t;

static __device__ __forceinline__ ushort_t f2bf(float x) {
    unsigned int u = __float_as_uint(x);
    unsigned int r = (u + 0x7fffu + ((u >> 16) & 1u)) >> 16;   // RNE
    return (ushort_t)r;
}

static __device__ __forceinline__ unsigned int cvt_pk_bf16(float a, float b) {
    unsigned int w;
    asm("v_cvt_pk_bf16_f32 %0, %1, %2" : "=v"(w) : "v"(a), "v"(b));
    return w;   // low 16 = a, high 16 = b
}

// ---------------- proj: h = h_in * proj_w + proj_b; writes fp32 h + bf16 hb --
__global__ __launch_bounds__(256) void proj_kernel(
    const float* __restrict__ hin, const float* __restrict__ w,
    const float* __restrict__ bias, float* __restrict__ hout,
    ushort_t* __restrict__ hb)
{
    long idx = (long)blockIdx.x * 256 + threadIdx.x;      // over B*N*64
    long bn = idx >> 6;
    int d4 = (int)(idx & 63) << 2;
    float hv = hin[bn];
    float4 wv = *(const float4*)&w[d4];
    float4 bv = *(const float4*)&bias[d4];
    float4 o;
    o.x = hv * wv.x + bv.x;
    o.y = hv * wv.y + bv.y;
    o.z = hv * wv.z + bv.z;
    o.w = hv * wv.w + bv.w;
    *(float4*)&hout[bn * D_ + d4] = o;
    ushortx4 ob;
    ob[0] = f2bf(o.x); ob[1] = f2bf(o.y); ob[2] = f2bf(o.z); ob[3] = f2bf(o.w);
    *(ushortx4*)&hb[bn * D_ + d4] = ob;
}

// ---------------- RoPE cos/sin table ----------------------------------------
__global__ __launch_bounds__(256) void rope_table_kernel(
    const float* __restrict__ pos, float* __restrict__ tab)
{
    int i = blockIdx.x * 256 + threadIdx.x;   // over B*N = 8192
    if (i >= B_ * N_) return;
    float t = pos[i * 2 + 0] * 64.0f;
    float x = pos[i * 2 + 1] * 64.0f;
    float* o = tab + (long)i * 32;
    const float log2_1e4_over8 = 13.28771237954945f / 8.0f;
    #pragma unroll
    for (int j = 0; j < 8; ++j) {
        float invf = exp2f(-(float)j * log2_1e4_over8);   // 10000^{-j/8}
        float st, ct, sx, cx;
        sincosf(t * invf, &st, &ct);
        sincosf(x * invf, &sx, &cx);
        o[j]      = ct;
        o[8 + j]  = st;
        o[16 + j] = cx;
        o[24 + j] = sx;
    }
}

// ---- merged prep: RoPE Q (prescaled) + K to head-major bf16, V transposed ---
__global__ __launch_bounds__(256) void prep_qkv(
    const float* __restrict__ qkv, const float* __restrict__ tab,
    ushort_t* __restrict__ Qb, ushort_t* __restrict__ Kb, ushort_t* __restrict__ Vt)
{
    const float F = 0.17677669529663687f * 1.4426950408889634f;  // scale * log2(e)
    int bh = blockIdx.y;
    int b = bh >> 3, h = bh & 7;
    int n0 = blockIdx.x << 6;
    int t = threadIdx.x;

    // ---- RoPE part: 64 tokens x 16 pairs = 1024 items, 4 per thread ----
    #pragma unroll
    for (int i = 0; i < 4; ++i) {
        int item = t + (i << 8);
        int tok = item >> 4, p = item & 15;
        long bn = (long)b * N_ + n0 + tok;
        int half = p >> 3, j = p & 7;
        const float* tb = tab + bn * 32;
        float c = tb[half * 16 + j];
        float s = tb[half * 16 + 8 + j];
        float cF = c * F, sF = s * F;
        long obase = ((long)bh * N_ + n0 + tok) * DH_;
        const float* base = qkv + bn * (3 * D_) + h * DH_ + half * 16 + j;
        int d0 = half * 16 + j;
        float q0 = base[0], q1 = base[8];
        Qb[obase + d0]     = f2bf(q0 * cF - q1 * sF);
        Qb[obase + d0 + 8] = f2bf(q1 * cF + q0 * sF);
        float k0 = base[D_], k1 = base[D_ + 8];
        Kb[obase + d0]     = f2bf(k0 * c - k1 * s);
        Kb[obase + d0 + 8] = f2bf(k1 * c + k0 * s);
    }

    // ---- V transpose part: 64 tokens x 32 dh via LDS ----
    __shared__ float T[64][36];
    int r = t >> 2, c0 = (t & 3) << 3;
    const float* src = qkv + ((long)b * N_ + n0 + r) * (3 * D_) + 2 * D_ + h * DH_ + c0;
    float4 a = ((const float4*)src)[0];
    float4 bb = ((const float4*)src)[1];
    *(float4*)&T[r][c0] = a;
    *(float4*)&T[r][c0 + 4] = bb;
    __syncthreads();
    int d = t >> 3, n8 = (t & 7) << 3;
    ushortx8 o;
    #pragma unroll
    for (int i = 0; i < 8; ++i) o[i] = f2bf(T[n8 + i][d]);
    *(ushortx8*)&Vt[((long)bh * DH_ + d) * N_ + n0 + n8] = o;
}

// ---- weight prep: fp32 W[K][N] -> bf16 WT[N][K], all matrices, one launch ---
__global__ __launch_bounds__(256) void wprep_kernel(
    const float* __restrict__ qkv_w, const float* __restrict__ out_w,
    const float* __restrict__ O_w, const float* __restrict__ ffn1_w,
    const float* __restrict__ ffn2_w, const float* __restrict__ final_w,
    ushort_t* __restrict__ WT)
{
    int bid = blockIdx.x;
    const float* src; ushort_t* dst; int K, Nn, tile;
    if (bid < 192)      { int l = bid / 48;        tile = bid % 48;        src = qkv_w  + (long)l * 196608; dst = WT + (long)l * 196608;           K = 256; Nn = 768; }
    else if (bid < 256) { int r = bid - 192; int l = r / 16; tile = r % 16; src = out_w  + (long)l * 65536;  dst = WT + 786432  + (long)l * 65536;  K = 256; Nn = 256; }
    else if (bid < 320) { int r = bid - 256; int l = r / 16; tile = r % 16; src = O_w    + (long)l * 65536;  dst = WT + 1048576 + (long)l * 65536;  K = 256; Nn = 256; }
    else if (bid < 448) { int r = bid - 320; int l = r / 32; tile = r % 32; src = ffn1_w + (long)l * 131072; dst = WT + 1310720 + (long)l * 131072; K = 256; Nn = 512; }
    else if (bid < 576) { int r = bid - 448; int l = r / 32; tile = r % 32; src = ffn2_w + (long)l * 131072; dst = WT + 1835008 + (long)l * 131072; K = 512; Nn = 256; }
    else                { tile = bid - 576;                                 src = final_w;                   dst = WT + 2359296;                    K = 256; Nn = 256; }
    int ntn = Nn >> 6;
    int kt = (tile / ntn) << 6;
    int nt = (tile % ntn) << 6;
    __shared__ float Tl[64][65];
    int t = threadIdx.x;
    int kr = t >> 2, nc0 = (t & 3) << 4;
    const float* sp = src + (long)(kt + kr) * Nn + nt + nc0;
    float4 v0 = ((const float4*)sp)[0];
    float4 v1 = ((const float4*)sp)[1];
    float4 v2 = ((const float4*)sp)[2];
    float4 v3 = ((const float4*)sp)[3];
    float* tr = &Tl[kr][nc0];
    tr[0] = v0.x; tr[1] = v0.y; tr[2] = v0.z; tr[3] = v0.w;
    tr[4] = v1.x; tr[5] = v1.y; tr[6] = v1.z; tr[7] = v1.w;
    tr[8] = v2.x; tr[9] = v2.y; tr[10] = v2.z; tr[11] = v2.w;
    tr[12] = v3.x; tr[13] = v3.y; tr[14] = v3.z; tr[15] = v3.w;
    __syncthreads();
    int n = t >> 2, kc0 = (t & 3) << 4;
    ushortx8 o0, o1;
    #pragma unroll
    for (int i = 0; i < 8; ++i) o0[i] = f2bf(Tl[kc0 + i][n]);
    #pragma unroll
    for (int i = 0; i < 8; ++i) o1[i] = f2bf(Tl[kc0 + 8 + i][n]);
    ushort_t* dp = dst + (long)(nt + n) * K + kt + kc0;
    *(ushortx8*)dp = o0;
    *(ushortx8*)(dp + 8) = o1;
}

// ---- fold W' = out_w @ O_w (fp32), write bf16 W'^T[n][k] --------------------
__global__ __launch_bounds__(256) void wfold_kernel(
    const float* __restrict__ out_w, const float* __restrict__ O_w,
    ushort_t* __restrict__ WTp)
{
    int l = blockIdx.x >> 4;
    int t4 = blockIdx.x & 15;
    int k0 = (t4 >> 2) << 6, n0 = (t4 & 3) << 6;
    const float* Am = out_w + (long)l * 65536;   // [k][j], 256x256
    const float* Bm = O_w + (long)l * 65536;     // [j][n]
    ushort_t* dst = WTp + (long)l * 65536;
    __shared__ float sA[16][68];
    __shared__ float sB[16][64];
    int tid = threadIdx.x;
    int tx = tid & 15, ty = tid >> 4;
    int arow = tid >> 2, acol = (tid & 3) << 2;
    int brow = tid >> 4, bcol = (tid & 15) << 2;
    const float* Aptr = Am + (long)(k0 + arow) * 256 + acol;
    const float* Bptr = Bm + (long)brow * 256 + n0 + bcol;
    float acc[4][4] = {{0.f}};
    for (int jt = 0; jt < 256; jt += 16) {
        float4 av = *(const float4*)(Aptr + jt);
        float4 bv = *(const float4*)(Bptr + (long)jt * 256);
        __syncthreads();
        sA[acol + 0][arow] = av.x;
        sA[acol + 1][arow] = av.y;
        sA[acol + 2][arow] = av.z;
        sA[acol + 3][arow] = av.w;
        *(float4*)&sB[brow][bcol] = bv;
        __syncthreads();
        #pragma unroll
        for (int kk = 0; kk < 16; ++kk) {
            float4 a = *(const float4*)&sA[kk][ty << 2];
            float4 b = *(const float4*)&sB[kk][tx << 2];
            acc[0][0] += a.x * b.x; acc[0][1] += a.x * b.y; acc[0][2] += a.x * b.z; acc[0][3] += a.x * b.w;
            acc[1][0] += a.y * b.x; acc[1][1] += a.y * b.y; acc[1][2] += a.y * b.z; acc[1][3] += a.y * b.w;
            acc[2][0] += a.z * b.x; acc[2][1] += a.z * b.y; acc[2][2] += a.z * b.z; acc[2][3] += a.z * b.w;
            acc[3][0] += a.w * b.x; acc[3][1] += a.w * b.y; acc[3][2] += a.w * b.z; acc[3][3] += a.w * b.w;
        }
    }
    #pragma unroll
    for (int i = 0; i < 4; ++i) {
        int k = k0 + (ty << 2) + i;
        #pragma unroll
        for (int c = 0; c < 4; ++c) {
            int n = n0 + (tx << 2) + c;
            dst[(long)n * 256 + k] = f2bf(acc[i][c]);
        }
    }
}

// ---- fold b' = out_b @ O_w + O_b (fp32), parallel: grid 32 = 4l x 8 chunks --
__global__ __launch_bounds__(256) void bfold_kernel(
    const float* __restrict__ out_b, const float* __restrict__ O_w,
    const float* __restrict__ O_b, float* __restrict__ bp)
{
    int l = blockIdx.x >> 3;
    int n = ((blockIdx.x & 7) << 5) + (threadIdx.x & 31);
    int jg = threadIdx.x >> 5;
    const float* Bm = O_w + (long)l * 65536;
    float acc = 0.f;
    #pragma unroll 8
    for (int j = jg * 32; j < jg * 32 + 32; ++j)
        acc += out_b[l * 256 + j] * Bm[(long)j * 256 + n];
    __shared__ float red[8][32];
    red[jg][threadIdx.x & 31] = acc;
    __syncthreads();
    if (threadIdx.x < 32) {
        int nn = ((blockIdx.x & 7) << 5) + threadIdx.x;
        float s = O_b[l * 256 + nn];
        #pragma unroll
        for (int g = 0; g < 8; ++g) s += red[g][threadIdx.x];
        bp[l * 256 + nn] = s;
    }
}

// ---------------- bf16 MFMA GEMM, 128x64 tile, BK=64, gload_lds pipeline -----
// C = A[M][K] @ BT[N][K]^T. flags: 1=bias, 2=relu, 4=bf16 output
__global__ __launch_bounds__(256) void gemm_mfma2(
    const ushort_t* __restrict__ A, const ushort_t* __restrict__ BT,
    const float* __restrict__ bias, void* __restrict__ Cout,
    int N, int K, int flags)
{
    __shared__ ushort_t sA[2][8192];    // [buf][128 rows][64 k]
    __shared__ ushort_t sB[2][4096];    // [buf][64 rows][64 k]
    int tid = threadIdx.x;
    int wid = tid >> 6, lane = tid & 63;
    int lo = lane & 15, hi = lane >> 4;
    int wm = wid >> 1, wn = wid & 1;
    int m0 = blockIdx.y << 7, n0 = blockIdx.x << 6;

    // staging: each lane sources global with pre-swizzled k-slot (rule #21)
    int lrow = lane >> 3;          // 0..7
    int slot = lane & 7;
    const ushort_t* Ag[4];
    const ushort_t* Bg[2];
    #pragma unroll
    for (int c = 0; c < 4; ++c) {
        int arow = (wid << 5) + (c << 3) + lrow;
        Ag[c] = A + (long)(m0 + arow) * K + ((slot ^ lrow) << 3);
    }
    #pragma unroll
    for (int c = 0; c < 2; ++c) {
        int brow = (wid << 4) + (c << 3) + lrow;
        Bg[c] = BT + (long)(n0 + brow) * K + ((slot ^ lrow) << 3);
    }

#define STAGE(buf, koff) do { \
    _Pragma("unroll") \
    for (int c = 0; c < 4; ++c) \
        __builtin_amdgcn_global_load_lds((const glb_u32_t*)(Ag[c] + (koff)), \
            (lds_u32_t*)&sA[buf][((wid << 5) + (c << 3)) << 6], 16, 0, 0); \
    _Pragma("unroll") \
    for (int c = 0; c < 2; ++c) \
        __builtin_amdgcn_global_load_lds((const glb_u32_t*)(Bg[c] + (koff)), \
            (lds_u32_t*)&sB[buf][((wid << 4) + (c << 3)) << 6], 16, 0, 0); \
} while (0)

    f32x4 acc[4][2];
    #pragma unroll
    for (int i = 0; i < 4; ++i)
        #pragma unroll
        for (int j = 0; j < 2; ++j) acc[i][j] = (f32x4){0.f, 0.f, 0.f, 0.f};

    int ar[4], br[2];
    #pragma unroll
    for (int mf = 0; mf < 4; ++mf) ar[mf] = ((wm << 6) + (mf << 4) + lo) << 6;
    #pragma unroll
    for (int nf = 0; nf < 2; ++nf) br[nf] = ((wn << 5) + (nf << 4) + lo) << 6;
    int swz = lo & 7;

    int nk = K >> 6;
    STAGE(0, 0);
    for (int s = 0; s < nk; ++s) {
        int buf = s & 1;
        if (s + 1 < nk) {
            STAGE(buf ^ 1, (s + 1) << 6);
            asm volatile("s_waitcnt vmcnt(6)" ::: "memory");
        } else {
            asm volatile("s_waitcnt vmcnt(0)" ::: "memory");
        }
        __builtin_amdgcn_s_barrier();
        asm volatile("" ::: "memory");
        #pragma unroll
        for (int ks = 0; ks < 2; ++ks) {
            int ko = (((ks << 2) + hi) ^ swz) << 3;
            short8 a0 = *(const short8*)&sA[buf][ar[0] + ko];
            short8 a1 = *(const short8*)&sA[buf][ar[1] + ko];
            short8 a2 = *(const short8*)&sA[buf][ar[2] + ko];
            short8 a3 = *(const short8*)&sA[buf][ar[3] + ko];
            short8 b0 = *(const short8*)&sB[buf][br[0] + ko];
            short8 b1 = *(const short8*)&sB[buf][br[1] + ko];
            acc[0][0] = __builtin_amdgcn_mfma_f32_16x16x32_bf16(a0, b0, acc[0][0], 0, 0, 0);
            acc[0][1] = __builtin_amdgcn_mfma_f32_16x16x32_bf16(a0, b1, acc[0][1], 0, 0, 0);
            acc[1][0] = __builtin_amdgcn_mfma_f32_16x16x32_bf16(a1, b0, acc[1][0], 0, 0, 0);
            acc[1][1] = __builtin_amdgcn_mfma_f32_16x16x32_bf16(a1, b1, acc[1][1], 0, 0, 0);
            acc[2][0] = __builtin_amdgcn_mfma_f32_16x16x32_bf16(a2, b0, acc[2][0], 0, 0, 0);
            acc[2][1] = __builtin_amdgcn_mfma_f32_16x16x32_bf16(a2, b1, acc[2][1], 0, 0, 0);
            acc[3][0] = __builtin_amdgcn_mfma_f32_16x16x32_bf16(a3, b0, acc[3][0], 0, 0, 0);
            acc[3][1] = __builtin_amdgcn_mfma_f32_16x16x32_bf16(a3, b1, acc[3][1], 0, 0, 0);
        }
        asm volatile("" ::: "memory");
        __builtin_amdgcn_s_barrier();
    }
#undef STAGE

    #pragma unroll
    for (int nf = 0; nf < 2; ++nf) {
        int col = n0 + (wn << 5) + (nf << 4) + lo;
        float bv = (flags & 1) ? bias[col] : 0.f;
        #pragma unroll
        for (int mf = 0; mf < 4; ++mf) {
            #pragma unroll
            for (int j = 0; j < 4; ++j) {
                float v = acc[mf][nf][j] + bv;
                if (flags & 2) v = fmaxf(v, 0.f);
                long row = m0 + (wm << 6) + (mf << 4) + (hi << 2) + j;
                if (flags & 4) ((ushort_t*)Cout)[row * N + col] = f2bf(v);
                else           ((float*)Cout)[row * N + col] = v;
            }
        }
    }
}

// ---------------- split-K zero-LDS flash attention ---------------------------
// grid (32 = 16 qtiles x 2 ksplit, B*H), 256 thr (4 waves x 32 q).
// Each block: 1024 keys. Outputs unnormalized O fp32 + per-q (m,l) partials.
// l via VALU in-lane sum + shfl_xor(32) (round-7-verified). Register prefetch.
__global__ __launch_bounds__(256) void attn_split(
    const ushort_t* __restrict__ Qb, const ushort_t* __restrict__ Kb,
    const ushort_t* __restrict__ Vt, float* __restrict__ Op,
    float2* __restrict__ ml)
{
    int bh = blockIdx.y;
    int qt = blockIdx.x & 15, sp = blockIdx.x >> 4;
    int tid = threadIdx.x;
    int wid = tid >> 6, lane = tid & 63;
    int lq = lane & 31;
    int half = lane >> 5;
    int qbase = (qt << 7) + wid * 32;

    const ushort_t* Qp = Qb + (long)bh * N_ * DH_;
    const ushort_t* kp = Kb + (long)bh * N_ * DH_ + ((long)sp << 10) * DH_ + lq * DH_ + half * 8;
    const ushort_t* vp = Vt + (long)bh * DH_ * N_ + (long)lq * N_ + (sp << 10) + half * 8;

    short8 qf0 = *(const short8*)&Qp[(long)(qbase + lq) * DH_ + half * 8];
    short8 qf1 = *(const short8*)&Qp[(long)(qbase + lq) * DH_ + 16 + half * 8];

    f32x16 acc;
    #pragma unroll
    for (int r = 0; r < 16; ++r) acc[r] = 0.f;
    float m = -1e30f, lsum = 0.f;

    // prologue: fragments for first 64 keys of this split
    short8 k00 = *(const short8*)(kp +  0 * DH_);
    short8 k01 = *(const short8*)(kp +  0 * DH_ + 16);
    short8 k10 = *(const short8*)(kp + 32 * DH_);
    short8 k11 = *(const short8*)(kp + 32 * DH_ + 16);
    short8 v00 = *(const short8*)(vp +  0);
    short8 v01 = *(const short8*)(vp + 16);
    short8 v10 = *(const short8*)(vp + 32);
    short8 v11 = *(const short8*)(vp + 48);

#define ATTN_TILE(K00, K01, K10, K11, V00, V01, V10, V11) do {                  \
    f32x16 sa, sb;                                                              \
    _Pragma("unroll")                                                           \
    for (int r = 0; r < 16; ++r) { sa[r] = 0.f; sb[r] = 0.f; }                  \
    sa = __builtin_amdgcn_mfma_f32_32x32x16_bf16(K00, qf0, sa, 0, 0, 0);        \
    sa = __builtin_amdgcn_mfma_f32_32x32x16_bf16(K01, qf1, sa, 0, 0, 0);        \
    sb = __builtin_amdgcn_mfma_f32_32x32x16_bf16(K10, qf0, sb, 0, 0, 0);        \
    sb = __builtin_amdgcn_mfma_f32_32x32x16_bf16(K11, qf1, sb, 0, 0, 0);        \
    float pmax = fmaxf(sa[0], sb[0]);                                           \
    _Pragma("unroll")                                                           \
    for (int r = 1; r < 16; ++r) pmax = fmaxf(pmax, fmaxf(sa[r], sb[r]));       \
    pmax = fmaxf(pmax, __shfl_xor(pmax, 32, 64));                               \
    if (!__all(pmax <= m + 8.f)) {                                              \
        float mn = fmaxf(m, pmax);                                              \
        float corr = __builtin_amdgcn_exp2f(m - mn);                            \
        m = mn; lsum *= corr;                                                   \
        _Pragma("unroll")                                                       \
        for (int r = 0; r < 16; ++r) {                                          \
            int qr = (r & 3) + 8 * (r >> 2) + 4 * half;                         \
            acc[r] *= __shfl(corr, qr, 64);                                     \
        }                                                                       \
    }                                                                           \
    float sum = 0.f;                                                            \
    _Pragma("unroll")                                                           \
    for (int r = 0; r < 16; ++r) {                                              \
        sa[r] = __builtin_amdgcn_exp2f(sa[r] - m); sum += sa[r];                \
        sb[r] = __builtin_amdgcn_exp2f(sb[r] - m); sum += sb[r];                \
    }                                                                           \
    sum += __shfl_xor(sum, 32, 64);                                             \
    lsum += sum;                                                                \
    unsigned int a0 = cvt_pk_bf16(sa[0], sa[1]),   a1 = cvt_pk_bf16(sa[2], sa[3]);   \
    unsigned int a2 = cvt_pk_bf16(sa[4], sa[5]),   a3 = cvt_pk_bf16(sa[6], sa[7]);   \
    unsigned int a4 = cvt_pk_bf16(sa[8], sa[9]),   a5 = cvt_pk_bf16(sa[10], sa[11]); \
    unsigned int a6 = cvt_pk_bf16(sa[12], sa[13]), a7 = cvt_pk_bf16(sa[14], sa[15]); \
    unsigned int b0 = cvt_pk_bf16(sb[0], sb[1]),   b1 = cvt_pk_bf16(sb[2], sb[3]);   \
    unsigned int b2 = cvt_pk_bf16(sb[4], sb[5]),   b3 = cvt_pk_bf16(sb[6], sb[7]);   \
    unsigned int b4 = cvt_pk_bf16(sb[8], sb[9]),   b5 = cvt_pk_bf16(sb[10], sb[11]); \
    unsigned int b6 = cvt_pk_bf16(sb[12], sb[13]), b7 = cvt_pk_bf16(sb[14], sb[15]); \
    asm volatile("v_permlane32_swap_b32 %0, %1" : "+v"(a0), "+v"(a2));          \
    asm volatile("v_permlane32_swap_b32 %0, %1" : "+v"(a1), "+v"(a3));          \
    asm volatile("v_permlane32_swap_b32 %0, %1" : "+v"(a4), "+v"(a6));          \
    asm volatile("v_permlane32_swap_b32 %0, %1" : "+v"(a5), "+v"(a7));          \
    asm volatile("v_permlane32_swap_b32 %0, %1" : "+v"(b0), "+v"(b2));          \
    asm volatile("v_permlane32_swap_b32 %0, %1" : "+v"(b1), "+v"(b3));          \
    asm volatile("v_permlane32_swap_b32 %0, %1" : "+v"(b4), "+v"(b6));          \
    asm volatile("v_permlane32_swap_b32 %0, %1" : "+v"(b5), "+v"(b7));          \
    union { unsigned int u[4]; short8 s8; } p0, p1, p2, p3;                     \
    p0.u[0] = a0; p0.u[1] = a1; p0.u[2] = a2; p0.u[3] = a3;                     \
    p1.u[0] = a4; p1.u[1] = a5; p1.u[2] = a6; p1.u[3] = a7;                     \
    p2.u[0] = b0; p2.u[1] = b1; p2.u[2] = b2; p2.u[3] = b3;                     \
    p3.u[0] = b4; p3.u[1] = b5; p3.u[2] = b6; p3.u[3] = b7;                     \
    acc = __builtin_amdgcn_mfma_f32_32x32x16_bf16(p0.s8, V00, acc, 0, 0, 0);    \
    acc = __builtin_amdgcn_mfma_f32_32x32x16_bf16(p1.s8, V01, acc, 0, 0, 0);    \
    acc = __builtin_amdgcn_mfma_f32_32x32x16_bf16(p2.s8, V10, acc, 0, 0, 0);    \
    acc = __builtin_amdgcn_mfma_f32_32x32x16_bf16(p3.s8, V11, acc, 0, 0, 0);    \
} while (0)

    const int NITER = 1024 / 64;       // 16 iterations per split
    for (int it = 0; it < NITER - 1; ++it) {
        long kn = (long)(it + 1) << 6;
        short8 nk00 = *(const short8*)(kp + (kn +  0) * DH_);
        short8 nk01 = *(const short8*)(kp + (kn +  0) * DH_ + 16);
        short8 nk10 = *(const short8*)(kp + (kn + 32) * DH_);
        short8 nk11 = *(const short8*)(kp + (kn + 32) * DH_ + 16);
        short8 nv00 = *(const short8*)(vp + kn);
        short8 nv01 = *(const short8*)(vp + kn + 16);
        short8 nv10 = *(const short8*)(vp + kn + 32);
        short8 nv11 = *(const short8*)(vp + kn + 48);
        ATTN_TILE(k00, k01, k10, k11, v00, v01, v10, v11);
        k00 = nk00; k01 = nk01; k10 = nk10; k11 = nk11;
        v00 = nv00; v01 = nv01; v10 = nv10; v11 = nv11;
    }
    ATTN_TILE(k00, k01, k10, k11, v00, v01, v10, v11);
#undef ATTN_TILE

    // epilogue: store unnormalized O fp32 and (m, l) per q.
    // Lanes 0..31 hold (m, lsum) for q = lq exactly (both halves identical
    // after the shfl_xor(32) reductions) -> simple provably-correct write.
    float* OpB = Op + (long)sp * 2097152;
    float2* mlB = ml + (long)sp * 65536;
    #pragma unroll
    for (int r = 0; r < 16; ++r) {
        int qr = (r & 3) + 8 * (r >> 2) + 4 * half;
        long row = (long)bh * N_ + qbase + qr;
        OpB[row * 32 + lq] = acc[r];
    }
    if (lane < 32) mlB[(long)bh * N_ + qbase + lq] = make_float2(m, lsum);
}

// ---- combine 2 split partials -> bf16 attention output ----------------------
__global__ __launch_bounds__(256) void attn_combine(
    const float* __restrict__ Op, const float2* __restrict__ ml,
    ushort_t* __restrict__ o)
{
    int i = blockIdx.x * 256 + threadIdx.x;    // over B*H*N = 65536 q-rows
    int bh = i >> 11, q = i & 2047;
    int b = bh >> 3, h = bh & 7;
    float2 m0 = ml[i];
    float2 m1 = ml[65536 + i];
    float mn = fmaxf(m0.x, m1.x);
    float c0 = __builtin_amdgcn_exp2f(m0.x - mn);
    float c1 = __builtin_amdgcn_exp2f(m1.x - mn);
    float inv = 1.f / (c0 * m0.y + c1 * m1.y);
    float f0 = c0 * inv, f1 = c1 * inv;
    const f32x4* O0 = (const f32x4*)(Op + (long)i * 32);
    const f32x4* O1 = (const f32x4*)(Op + 2097152 + (long)i * 32);
    unsigned int w[16];
    #pragma unroll
    for (int v = 0; v < 8; ++v) {
        f32x4 a = O0[v], bb = O1[v];
        float e0 = f0 * a[0] + f1 * bb[0];
        float e1 = f0 * a[1] + f1 * bb[1];
        float e2 = f0 * a[2] + f1 * bb[2];
        float e3 = f0 * a[3] + f1 * bb[3];
        w[2 * v]     = cvt_pk_bf16(e0, e1);
        w[2 * v + 1] = cvt_pk_bf16(e2, e3);
    }
    uint4* dst = (uint4*)&o[((long)b * N_ + q) * D_ + h * DH_];
    dst[0] = make_uint4(w[0], w[1], w[2], w[3]);
    dst[1] = make_uint4(w[4], w[5], w[6], w[7]);
    dst[2] = make_uint4(w[8], w[9], w[10], w[11]);
    dst[3] = make_uint4(w[12], w[13], w[14], w[15]);
}

// ---------------- fused residual add + LayerNorm; writes fp32 h + bf16 hb ----
__global__ __launch_bounds__(256) void add_ln_kernel(
    float* __restrict__ h, const float* __restrict__ r,
    const float* __restrict__ g, const float* __restrict__ be,
    ushort_t* __restrict__ hb)
{
    int row = blockIdx.x * 4 + (threadIdx.x >> 6);
    int lane = threadIdx.x & 63;
    long off = (long)row * D_ + (lane << 2);
    float4 x = *(float4*)&h[off];
    float4 rr = *(const float4*)&r[off];
    x.x += rr.x; x.y += rr.y; x.z += rr.z; x.w += rr.w;
    float s = x.x + x.y + x.z + x.w;
    #pragma unroll
    for (int k = 1; k < 64; k <<= 1) s += __shfl_xor(s, k, 64);
    float mean = s * (1.f / 256.f);
    float dx = x.x - mean, dy = x.y - mean, dz = x.z - mean, dw = x.w - mean;
    float sq = dx * dx + dy * dy + dz * dz + dw * dw;
    #pragma unroll
    for (int k = 1; k < 64; k <<= 1) sq += __shfl_xor(sq, k, 64);
    float rstd = rsqrtf(sq * (1.f / 256.f) + 1e-5f);
    float4 gv = *(const float4*)&g[lane << 2];
    float4 bv = *(const float4*)&be[lane << 2];
    float4 o;
    o.x = dx * rstd * gv.x + bv.x;
    o.y = dy * rstd * gv.y + bv.y;
    o.z = dz * rstd * gv.z + bv.z;
    o.w = dw * rstd * gv.w + bv.w;
    *(float4*)&h[off] = o;
    ushortx4 ob;
    ob[0] = f2bf(o.x); ob[1] = f2bf(o.y); ob[2] = f2bf(o.z); ob[3] = f2bf(o.w);
    *(ushortx4*)&hb[off] = ob;
}

extern "C" void kernel_launch(void* const* d_in, const int* in_sizes, int n_in,
                              void* d_out, int out_size, void* d_ws, size_t ws_size,
                              hipStream_t stream) {
    const float* h_in    = (const float*)d_in[0];
    const float* pos     = (const float*)d_in[1];
    const float* proj_w  = (const float*)d_in[2];
    const float* proj_b  = (const float*)d_in[3];
    const float* qkv_w   = (const float*)d_in[4];
    const float* out_w   = (const float*)d_in[5];
    const float* out_b   = (const float*)d_in[6];
    const float* O_w     = (const float*)d_in[7];
    const float* O_b     = (const float*)d_in[8];
    const float* ffn1_w  = (const float*)d_in[9];
    const float* ffn1_b  = (const float*)d_in[10];
    const float* ffn2_w  = (const float*)d_in[11];
    const float* ffn2_b  = (const float*)d_in[12];
    const float* ln1_g   = (const float*)d_in[13];
    const float* ln1_b   = (const float*)d_in[14];
    const float* ln2_g   = (const float*)d_in[15];
    const float* ln2_b   = (const float*)d_in[16];
    const float* final_w = (const float*)d_in[17];
    float* out = (float*)d_out;

    float* ws   = (float*)d_ws;
    float* h    = ws;                    // 2,097,152 f
    float* hb_f = h + 2097152;           // 1,048,576 f (bf16 h)
    float* tab  = hb_f + 1048576;        //   262,144 f
    float* WT_f = tab + 262144;          // 1,212,416 f (bf16 weights^T)
    float* R    = WT_f + 1212416;        // 6,291,456 f (qkv fp32, later temps)
    float* QKV  = R + 6291456;           // 3,145,728 f (Qb,Kb,Vt bf16)
    float* tf   = QKV + 3145728;         // 2,097,152 f (W'/b' folds + ml)

    ushort_t* hb  = (ushort_t*)hb_f;
    ushort_t* WT  = (ushort_t*)WT_f;
    float*    qkvf = R;
    ushort_t* aob = (ushort_t*)R;                    // attn out (qkv dead after prep)
    float*    Op  = R + 2097152;                     // 4,194,304 f: split O partials
    ushort_t* fb  = (ushort_t*)(R + 2097152);        // ffn1 out bf16 (overwrites Op[0])
    float*    tf32 = R + 4194304;                    // fp32 GEMM out (overwrites Op[1])
    ushort_t* Qb  = (ushort_t*)QKV;
    ushort_t* Kb  = Qb + 2097152;
    ushort_t* Vtg = Kb + 2097152;
    ushort_t* WTp = (ushort_t*)tf;                   // 4 x 65536 bf16
    float*    bp  = tf + 131072;                     // 4 x 256 f32
    float2*   mlb = (float2*)(tf + 262144);          // 2 x 65536 float2

    const long qkvT_off  = 0;
    const long ffn1T_off = 1310720;
    const long ffn2T_off = 1835008;
    const long finT_off  = 2359296;

    const long M = (long)B_ * N_;    // 8192 rows

    wprep_kernel<<<592, 256, 0, stream>>>(qkv_w, out_w, O_w, ffn1_w, ffn2_w, final_w, WT);
    wfold_kernel<<<64, 256, 0, stream>>>(out_w, O_w, WTp);
    bfold_kernel<<<32, 256, 0, stream>>>(out_b, O_w, O_b, bp);
    proj_kernel<<<(M * 64) / 256, 256, 0, stream>>>(h_in, proj_w, proj_b, h, hb);
    rope_table_kernel<<<(B_ * N_) / 256, 256, 0, stream>>>(pos, tab);

    for (int l = 0; l < L_; ++l) {
        // qkv = hb @ qkv_w[l] -> fp32 qkvf   (N=768, K=256)
        gemm_mfma2<<<dim3(768 / 64, M / 128), 256, 0, stream>>>(
            hb, WT + qkvT_off + (long)l * 196608, nullptr, qkvf, 768, 256, 0);
        // merged RoPE + V-transpose -> Qb, Kb, Vtg
        prep_qkv<<<dim3(N_ / 64, B_ * H_), 256, 0, stream>>>(qkvf, tab, Qb, Kb, Vtg);
        // split-K flash attention -> Op, ml partials
        attn_split<<<dim3(32, B_ * H_), 256, 0, stream>>>(Qb, Kb, Vtg, Op, mlb);
        // combine -> aob (bf16)
        attn_combine<<<256, 256, 0, stream>>>(Op, mlb, aob);
        // aob @ W'(out@O) + b' -> tf32 (fp32)  (N=256, K=256)
        gemm_mfma2<<<dim3(256 / 64, M / 128), 256, 0, stream>>>(
            aob, WTp + (long)l * 65536, bp + (long)l * 256, tf32, 256, 256, 1);
        // h = LN(h + tf32) -> h, hb
        add_ln_kernel<<<M / 4, 256, 0, stream>>>(
            h, tf32, ln1_g + (long)l * D_, ln1_b + (long)l * D_, hb);
        // ffn1: relu(hb @ ffn1_w + b) -> fb (bf16)  (N=512, K=256)
        gemm_mfma2<<<dim3(512 / 64, M / 128), 256, 0, stream>>>(
            hb, WT + ffn1T_off + (long)l * 131072, ffn1_b + (long)l * 2 * D_, fb, 512, 256, 1 | 2 | 4);
        // ffn2: fb @ ffn2_w + b -> tf32 (fp32)  (N=256, K=512)
        gemm_mfma2<<<dim3(256 / 64, M / 128), 256, 0, stream>>>(
            fb, WT + ffn2T_off + (long)l * 131072, ffn2_b + (long)l * D_, tf32, 256, 512, 1);
        // h = LN(h + tf32) -> h, hb
        add_ln_kernel<<<M / 4, 256, 0, stream>>>(
            h, tf32, ln2_g + (long)l * D_, ln2_b + (long)l * D_, hb);
    }
    // final: hb @ final_w -> out (fp32, no bias)
    gemm_mfma2<<<dim3(256 / 64, M / 128), 256, 0, stream>>>(
        hb, WT + finT_off, nullptr, out, 256, 256, 0);
}

// Round 10
// 551.392 us; speedup vs baseline: 1.0785x; 1.0785x over previous
//
#include <hip/hip_runtime.h>
#include <math.h>

#define B_ 4
#define N_ 2048
#define D_ 256
#define H_ 8
#define L_ 4
#define DH_ 32

typedef float f32x4 __attribute__((ext_vector_type(4)));
typedef float f32x16 __attribute__((ext_vector_type(16)));
typedef short short8 __attribute__((ext_vector_type(8)));
typedef unsigned short ushort_t;
typedef ushort_t ushortx4 __attribute__((ext_vector_type(4)));
typedef ushort_t ushortx8 __attribute__((ext_vector_type(8)));

typedef __attribute__((address_space(3))) unsigned int lds_u32_t;
typedef __attribute__((address_space(1))) unsigned int glb_u32_t;

static __device__ __forceinline__ ushort_t f2bf(float x) {
    unsigned int u = __float_as_uint(x);
    unsigned int r = (u + 0x7fffu + ((u >> 16) & 1u)) >> 16;   // RNE
    return (ushort_t)r;
}

static __device__ __forceinline__ unsigned int cvt_pk_bf16(float a, float b) {
    unsigned int w;
    asm("v_cvt_pk_bf16_f32 %0, %1, %2" : "=v"(w) : "v"(a), "v"(b));
    return w;   // low 16 = a, high 16 = b
}

// cross-half (lane ^ 32) reduce via v_permlane32_swap: after swap of (a=x,b=x),
// a[l]=x[l<32? l : l-32], b[l]=x[l<32? l+32 : l] -> op(a,b) == op(self,partner)
static __device__ __forceinline__ float xhalf_max(float x) {
    unsigned int a = __float_as_uint(x), b = a;
    asm volatile("v_permlane32_swap_b32 %0, %1" : "+v"(a), "+v"(b));
    return fmaxf(__uint_as_float(a), __uint_as_float(b));
}
static __device__ __forceinline__ float xhalf_add(float x) {
    unsigned int a = __float_as_uint(x), b = a;
    asm volatile("v_permlane32_swap_b32 %0, %1" : "+v"(a), "+v"(b));
    return __uint_as_float(a) + __uint_as_float(b);
}

// ---------------- proj: h = h_in * proj_w + proj_b; writes fp32 h + bf16 hb --
__global__ __launch_bounds__(256) void proj_kernel(
    const float* __restrict__ hin, const float* __restrict__ w,
    const float* __restrict__ bias, float* __restrict__ hout,
    ushort_t* __restrict__ hb)
{
    long idx = (long)blockIdx.x * 256 + threadIdx.x;      // over B*N*64
    long bn = idx >> 6;
    int d4 = (int)(idx & 63) << 2;
    float hv = hin[bn];
    float4 wv = *(const float4*)&w[d4];
    float4 bv = *(const float4*)&bias[d4];
    float4 o;
    o.x = hv * wv.x + bv.x;
    o.y = hv * wv.y + bv.y;
    o.z = hv * wv.z + bv.z;
    o.w = hv * wv.w + bv.w;
    *(float4*)&hout[bn * D_ + d4] = o;
    ushortx4 ob;
    ob[0] = f2bf(o.x); ob[1] = f2bf(o.y); ob[2] = f2bf(o.z); ob[3] = f2bf(o.w);
    *(ushortx4*)&hb[bn * D_ + d4] = ob;
}

// ---------------- RoPE cos/sin table ----------------------------------------
__global__ __launch_bounds__(256) void rope_table_kernel(
    const float* __restrict__ pos, float* __restrict__ tab)
{
    int i = blockIdx.x * 256 + threadIdx.x;   // over B*N = 8192
    if (i >= B_ * N_) return;
    float t = pos[i * 2 + 0] * 64.0f;
    float x = pos[i * 2 + 1] * 64.0f;
    float* o = tab + (long)i * 32;
    const float log2_1e4_over8 = 13.28771237954945f / 8.0f;
    #pragma unroll
    for (int j = 0; j < 8; ++j) {
        float invf = exp2f(-(float)j * log2_1e4_over8);   // 10000^{-j/8}
        float st, ct, sx, cx;
        sincosf(t * invf, &st, &ct);
        sincosf(x * invf, &sx, &cx);
        o[j]      = ct;
        o[8 + j]  = st;
        o[16 + j] = cx;
        o[24 + j] = sx;
    }
}

// ---- merged prep: RoPE Q (prescaled) + K to head-major bf16, V transposed ---
__global__ __launch_bounds__(256) void prep_qkv(
    const float* __restrict__ qkv, const float* __restrict__ tab,
    ushort_t* __restrict__ Qb, ushort_t* __restrict__ Kb, ushort_t* __restrict__ Vt)
{
    const float F = 0.17677669529663687f * 1.4426950408889634f;  // scale * log2(e)
    int bh = blockIdx.y;
    int b = bh >> 3, h = bh & 7;
    int n0 = blockIdx.x << 6;
    int t = threadIdx.x;

    // ---- RoPE part: 64 tokens x 16 pairs = 1024 items, 4 per thread ----
    #pragma unroll
    for (int i = 0; i < 4; ++i) {
        int item = t + (i << 8);
        int tok = item >> 4, p = item & 15;
        long bn = (long)b * N_ + n0 + tok;
        int half = p >> 3, j = p & 7;
        const float* tb = tab + bn * 32;
        float c = tb[half * 16 + j];
        float s = tb[half * 16 + 8 + j];
        float cF = c * F, sF = s * F;
        long obase = ((long)bh * N_ + n0 + tok) * DH_;
        const float* base = qkv + bn * (3 * D_) + h * DH_ + half * 16 + j;
        int d0 = half * 16 + j;
        float q0 = base[0], q1 = base[8];
        Qb[obase + d0]     = f2bf(q0 * cF - q1 * sF);
        Qb[obase + d0 + 8] = f2bf(q1 * cF + q0 * sF);
        float k0 = base[D_], k1 = base[D_ + 8];
        Kb[obase + d0]     = f2bf(k0 * c - k1 * s);
        Kb[obase + d0 + 8] = f2bf(k1 * c + k0 * s);
    }

    // ---- V transpose part: 64 tokens x 32 dh via LDS ----
    __shared__ float T[64][36];
    int r = t >> 2, c0 = (t & 3) << 3;
    const float* src = qkv + ((long)b * N_ + n0 + r) * (3 * D_) + 2 * D_ + h * DH_ + c0;
    float4 a = ((const float4*)src)[0];
    float4 bb = ((const float4*)src)[1];
    *(float4*)&T[r][c0] = a;
    *(float4*)&T[r][c0 + 4] = bb;
    __syncthreads();
    int d = t >> 3, n8 = (t & 7) << 3;
    ushortx8 o;
    #pragma unroll
    for (int i = 0; i < 8; ++i) o[i] = f2bf(T[n8 + i][d]);
    *(ushortx8*)&Vt[((long)bh * DH_ + d) * N_ + n0 + n8] = o;
}

// ---- weight prep: fp32 W[K][N] -> bf16 WT[N][K], all matrices, one launch ---
__global__ __launch_bounds__(256) void wprep_kernel(
    const float* __restrict__ qkv_w, const float* __restrict__ out_w,
    const float* __restrict__ O_w, const float* __restrict__ ffn1_w,
    const float* __restrict__ ffn2_w, const float* __restrict__ final_w,
    ushort_t* __restrict__ WT)
{
    int bid = blockIdx.x;
    const float* src; ushort_t* dst; int K, Nn, tile;
    if (bid < 192)      { int l = bid / 48;        tile = bid % 48;        src = qkv_w  + (long)l * 196608; dst = WT + (long)l * 196608;           K = 256; Nn = 768; }
    else if (bid < 256) { int r = bid - 192; int l = r / 16; tile = r % 16; src = out_w  + (long)l * 65536;  dst = WT + 786432  + (long)l * 65536;  K = 256; Nn = 256; }
    else if (bid < 320) { int r = bid - 256; int l = r / 16; tile = r % 16; src = O_w    + (long)l * 65536;  dst = WT + 1048576 + (long)l * 65536;  K = 256; Nn = 256; }
    else if (bid < 448) { int r = bid - 320; int l = r / 32; tile = r % 32; src = ffn1_w + (long)l * 131072; dst = WT + 1310720 + (long)l * 131072; K = 256; Nn = 512; }
    else if (bid < 576) { int r = bid - 448; int l = r / 32; tile = r % 32; src = ffn2_w + (long)l * 131072; dst = WT + 1835008 + (long)l * 131072; K = 512; Nn = 256; }
    else                { tile = bid - 576;                                 src = final_w;                   dst = WT + 2359296;                    K = 256; Nn = 256; }
    int ntn = Nn >> 6;
    int kt = (tile / ntn) << 6;
    int nt = (tile % ntn) << 6;
    __shared__ float Tl[64][65];
    int t = threadIdx.x;
    int kr = t >> 2, nc0 = (t & 3) << 4;
    const float* sp = src + (long)(kt + kr) * Nn + nt + nc0;
    float4 v0 = ((const float4*)sp)[0];
    float4 v1 = ((const float4*)sp)[1];
    float4 v2 = ((const float4*)sp)[2];
    float4 v3 = ((const float4*)sp)[3];
    float* tr = &Tl[kr][nc0];
    tr[0] = v0.x; tr[1] = v0.y; tr[2] = v0.z; tr[3] = v0.w;
    tr[4] = v1.x; tr[5] = v1.y; tr[6] = v1.z; tr[7] = v1.w;
    tr[8] = v2.x; tr[9] = v2.y; tr[10] = v2.z; tr[11] = v2.w;
    tr[12] = v3.x; tr[13] = v3.y; tr[14] = v3.z; tr[15] = v3.w;
    __syncthreads();
    int n = t >> 2, kc0 = (t & 3) << 4;
    ushortx8 o0, o1;
    #pragma unroll
    for (int i = 0; i < 8; ++i) o0[i] = f2bf(Tl[kc0 + i][n]);
    #pragma unroll
    for (int i = 0; i < 8; ++i) o1[i] = f2bf(Tl[kc0 + 8 + i][n]);
    ushort_t* dp = dst + (long)(nt + n) * K + kt + kc0;
    *(ushortx8*)dp = o0;
    *(ushortx8*)(dp + 8) = o1;
}

// ---- fold W' = out_w @ O_w (fp32), write bf16 W'^T[n][k] --------------------
__global__ __launch_bounds__(256) void wfold_kernel(
    const float* __restrict__ out_w, const float* __restrict__ O_w,
    ushort_t* __restrict__ WTp)
{
    int l = blockIdx.x >> 4;
    int t4 = blockIdx.x & 15;
    int k0 = (t4 >> 2) << 6, n0 = (t4 & 3) << 6;
    const float* Am = out_w + (long)l * 65536;   // [k][j], 256x256
    const float* Bm = O_w + (long)l * 65536;     // [j][n]
    ushort_t* dst = WTp + (long)l * 65536;
    __shared__ float sA[16][68];
    __shared__ float sB[16][64];
    int tid = threadIdx.x;
    int tx = tid & 15, ty = tid >> 4;
    int arow = tid >> 2, acol = (tid & 3) << 2;
    int brow = tid >> 4, bcol = (tid & 15) << 2;
    const float* Aptr = Am + (long)(k0 + arow) * 256 + acol;
    const float* Bptr = Bm + (long)brow * 256 + n0 + bcol;
    float acc[4][4] = {{0.f}};
    for (int jt = 0; jt < 256; jt += 16) {
        float4 av = *(const float4*)(Aptr + jt);
        float4 bv = *(const float4*)(Bptr + (long)jt * 256);
        __syncthreads();
        sA[acol + 0][arow] = av.x;
        sA[acol + 1][arow] = av.y;
        sA[acol + 2][arow] = av.z;
        sA[acol + 3][arow] = av.w;
        *(float4*)&sB[brow][bcol] = bv;
        __syncthreads();
        #pragma unroll
        for (int kk = 0; kk < 16; ++kk) {
            float4 a = *(const float4*)&sA[kk][ty << 2];
            float4 b = *(const float4*)&sB[kk][tx << 2];
            acc[0][0] += a.x * b.x; acc[0][1] += a.x * b.y; acc[0][2] += a.x * b.z; acc[0][3] += a.x * b.w;
            acc[1][0] += a.y * b.x; acc[1][1] += a.y * b.y; acc[1][2] += a.y * b.z; acc[1][3] += a.y * b.w;
            acc[2][0] += a.z * b.x; acc[2][1] += a.z * b.y; acc[2][2] += a.z * b.z; acc[2][3] += a.z * b.w;
            acc[3][0] += a.w * b.x; acc[3][1] += a.w * b.y; acc[3][2] += a.w * b.z; acc[3][3] += a.w * b.w;
        }
    }
    #pragma unroll
    for (int i = 0; i < 4; ++i) {
        int k = k0 + (ty << 2) + i;
        #pragma unroll
        for (int c = 0; c < 4; ++c) {
            int n = n0 + (tx << 2) + c;
            dst[(long)n * 256 + k] = f2bf(acc[i][c]);
        }
    }
}

// ---- fold b' = out_b @ O_w + O_b (fp32), parallel: grid 32 = 4l x 8 chunks --
__global__ __launch_bounds__(256) void bfold_kernel(
    const float* __restrict__ out_b, const float* __restrict__ O_w,
    const float* __restrict__ O_b, float* __restrict__ bp)
{
    int l = blockIdx.x >> 3;
    int n = ((blockIdx.x & 7) << 5) + (threadIdx.x & 31);
    int jg = threadIdx.x >> 5;
    const float* Bm = O_w + (long)l * 65536;
    float acc = 0.f;
    #pragma unroll 8
    for (int j = jg * 32; j < jg * 32 + 32; ++j)
        acc += out_b[l * 256 + j] * Bm[(long)j * 256 + n];
    __shared__ float red[8][32];
    red[jg][threadIdx.x & 31] = acc;
    __syncthreads();
    if (threadIdx.x < 32) {
        int nn = ((blockIdx.x & 7) << 5) + threadIdx.x;
        float s = O_b[l * 256 + nn];
        #pragma unroll
        for (int g = 0; g < 8; ++g) s += red[g][threadIdx.x];
        bp[l * 256 + nn] = s;
    }
}

// ---------------- bf16 MFMA GEMM, 128x64 tile, BK=64, gload_lds pipeline -----
// C = A[M][K] @ BT[N][K]^T. flags: 1=bias, 2=relu, 4=bf16 output
__global__ __launch_bounds__(256) void gemm_mfma2(
    const ushort_t* __restrict__ A, const ushort_t* __restrict__ BT,
    const float* __restrict__ bias, void* __restrict__ Cout,
    int N, int K, int flags)
{
    __shared__ ushort_t sA[2][8192];    // [buf][128 rows][64 k]
    __shared__ ushort_t sB[2][4096];    // [buf][64 rows][64 k]
    int tid = threadIdx.x;
    int wid = tid >> 6, lane = tid & 63;
    int lo = lane & 15, hi = lane >> 4;
    int wm = wid >> 1, wn = wid & 1;
    int m0 = blockIdx.y << 7, n0 = blockIdx.x << 6;

    // staging: each lane sources global with pre-swizzled k-slot (rule #21)
    int lrow = lane >> 3;          // 0..7
    int slot = lane & 7;
    const ushort_t* Ag[4];
    const ushort_t* Bg[2];
    #pragma unroll
    for (int c = 0; c < 4; ++c) {
        int arow = (wid << 5) + (c << 3) + lrow;
        Ag[c] = A + (long)(m0 + arow) * K + ((slot ^ lrow) << 3);
    }
    #pragma unroll
    for (int c = 0; c < 2; ++c) {
        int brow = (wid << 4) + (c << 3) + lrow;
        Bg[c] = BT + (long)(n0 + brow) * K + ((slot ^ lrow) << 3);
    }

#define STAGE(buf, koff) do { \
    _Pragma("unroll") \
    for (int c = 0; c < 4; ++c) \
        __builtin_amdgcn_global_load_lds((const glb_u32_t*)(Ag[c] + (koff)), \
            (lds_u32_t*)&sA[buf][((wid << 5) + (c << 3)) << 6], 16, 0, 0); \
    _Pragma("unroll") \
    for (int c = 0; c < 2; ++c) \
        __builtin_amdgcn_global_load_lds((const glb_u32_t*)(Bg[c] + (koff)), \
            (lds_u32_t*)&sB[buf][((wid << 4) + (c << 3)) << 6], 16, 0, 0); \
} while (0)

    f32x4 acc[4][2];
    #pragma unroll
    for (int i = 0; i < 4; ++i)
        #pragma unroll
        for (int j = 0; j < 2; ++j) acc[i][j] = (f32x4){0.f, 0.f, 0.f, 0.f};

    int ar[4], br[2];
    #pragma unroll
    for (int mf = 0; mf < 4; ++mf) ar[mf] = ((wm << 6) + (mf << 4) + lo) << 6;
    #pragma unroll
    for (int nf = 0; nf < 2; ++nf) br[nf] = ((wn << 5) + (nf << 4) + lo) << 6;
    int swz = lo & 7;

    int nk = K >> 6;
    STAGE(0, 0);
    for (int s = 0; s < nk; ++s) {
        int buf = s & 1;
        if (s + 1 < nk) {
            STAGE(buf ^ 1, (s + 1) << 6);
            asm volatile("s_waitcnt vmcnt(6)" ::: "memory");
        } else {
            asm volatile("s_waitcnt vmcnt(0)" ::: "memory");
        }
        __builtin_amdgcn_s_barrier();
        asm volatile("" ::: "memory");
        #pragma unroll
        for (int ks = 0; ks < 2; ++ks) {
            int ko = (((ks << 2) + hi) ^ swz) << 3;
            short8 a0 = *(const short8*)&sA[buf][ar[0] + ko];
            short8 a1 = *(const short8*)&sA[buf][ar[1] + ko];
            short8 a2 = *(const short8*)&sA[buf][ar[2] + ko];
            short8 a3 = *(const short8*)&sA[buf][ar[3] + ko];
            short8 b0 = *(const short8*)&sB[buf][br[0] + ko];
            short8 b1 = *(const short8*)&sB[buf][br[1] + ko];
            acc[0][0] = __builtin_amdgcn_mfma_f32_16x16x32_bf16(a0, b0, acc[0][0], 0, 0, 0);
            acc[0][1] = __builtin_amdgcn_mfma_f32_16x16x32_bf16(a0, b1, acc[0][1], 0, 0, 0);
            acc[1][0] = __builtin_amdgcn_mfma_f32_16x16x32_bf16(a1, b0, acc[1][0], 0, 0, 0);
            acc[1][1] = __builtin_amdgcn_mfma_f32_16x16x32_bf16(a1, b1, acc[1][1], 0, 0, 0);
            acc[2][0] = __builtin_amdgcn_mfma_f32_16x16x32_bf16(a2, b0, acc[2][0], 0, 0, 0);
            acc[2][1] = __builtin_amdgcn_mfma_f32_16x16x32_bf16(a2, b1, acc[2][1], 0, 0, 0);
            acc[3][0] = __builtin_amdgcn_mfma_f32_16x16x32_bf16(a3, b0, acc[3][0], 0, 0, 0);
            acc[3][1] = __builtin_amdgcn_mfma_f32_16x16x32_bf16(a3, b1, acc[3][1], 0, 0, 0);
        }
        asm volatile("" ::: "memory");
        __builtin_amdgcn_s_barrier();
    }
#undef STAGE

    #pragma unroll
    for (int nf = 0; nf < 2; ++nf) {
        int col = n0 + (wn << 5) + (nf << 4) + lo;
        float bv = (flags & 1) ? bias[col] : 0.f;
        #pragma unroll
        for (int mf = 0; mf < 4; ++mf) {
            #pragma unroll
            for (int j = 0; j < 4; ++j) {
                float v = acc[mf][nf][j] + bv;
                if (flags & 2) v = fmaxf(v, 0.f);
                long row = m0 + (wm << 6) + (mf << 4) + (hi << 2) + j;
                if (flags & 4) ((ushort_t*)Cout)[row * N + col] = f2bf(v);
                else           ((float*)Cout)[row * N + col] = v;
            }
        }
    }
}

// ---- one 64-key attention tile: tree-reduced softmax, permlane cross-half ---
static __device__ __forceinline__ void attn_tile(
    short8 K00, short8 K01, short8 K10, short8 K11,
    short8 V00, short8 V01, short8 V10, short8 V11,
    short8 qf0, short8 qf1, int half, const f32x16& Z,
    float& m, float& lsum, f32x16& acc)
{
    f32x16 sa = __builtin_amdgcn_mfma_f32_32x32x16_bf16(K00, qf0, Z, 0, 0, 0);
    sa = __builtin_amdgcn_mfma_f32_32x32x16_bf16(K01, qf1, sa, 0, 0, 0);
    f32x16 sb = __builtin_amdgcn_mfma_f32_32x32x16_bf16(K10, qf0, Z, 0, 0, 0);
    sb = __builtin_amdgcn_mfma_f32_32x32x16_bf16(K11, qf1, sb, 0, 0, 0);

    // balanced-tree max (depth ~5, max3-fusable) then cross-half permlane swap
    float mx[16];
    #pragma unroll
    for (int r = 0; r < 16; ++r) mx[r] = fmaxf(sa[r], sb[r]);
    #pragma unroll
    for (int st = 8; st >= 1; st >>= 1) {
        #pragma unroll
        for (int r = 0; r < st; ++r) mx[r] = fmaxf(mx[r], mx[r + st]);
    }
    float pmax = xhalf_max(mx[0]);

    if (!__all(pmax <= m + 8.f)) {          // defer-max (log2 units)
        float mn = fmaxf(m, pmax);
        float corr = __builtin_amdgcn_exp2f(m - mn);
        m = mn; lsum *= corr;
        #pragma unroll
        for (int r = 0; r < 16; ++r) {
            int qr = (r & 3) + 8 * (r >> 2) + 4 * half;
            acc[r] *= __shfl(corr, qr, 64);
        }
    }

    // p = exp2(s - m); balanced-tree sum
    float sm[16];
    #pragma unroll
    for (int r = 0; r < 16; ++r) {
        sa[r] = __builtin_amdgcn_exp2f(sa[r] - m);
        sb[r] = __builtin_amdgcn_exp2f(sb[r] - m);
        sm[r] = sa[r] + sb[r];
    }
    #pragma unroll
    for (int st = 8; st >= 1; st >>= 1) {
        #pragma unroll
        for (int r = 0; r < st; ++r) sm[r] += sm[r + st];
    }
    lsum += xhalf_add(sm[0]);

    // pack to bf16; permlane-swap into PV A-fragments
    unsigned int a0 = cvt_pk_bf16(sa[0], sa[1]),   a1 = cvt_pk_bf16(sa[2], sa[3]);
    unsigned int a2 = cvt_pk_bf16(sa[4], sa[5]),   a3 = cvt_pk_bf16(sa[6], sa[7]);
    unsigned int a4 = cvt_pk_bf16(sa[8], sa[9]),   a5 = cvt_pk_bf16(sa[10], sa[11]);
    unsigned int a6 = cvt_pk_bf16(sa[12], sa[13]), a7 = cvt_pk_bf16(sa[14], sa[15]);
    unsigned int b0 = cvt_pk_bf16(sb[0], sb[1]),   b1 = cvt_pk_bf16(sb[2], sb[3]);
    unsigned int b2 = cvt_pk_bf16(sb[4], sb[5]),   b3 = cvt_pk_bf16(sb[6], sb[7]);
    unsigned int b4 = cvt_pk_bf16(sb[8], sb[9]),   b5 = cvt_pk_bf16(sb[10], sb[11]);
    unsigned int b6 = cvt_pk_bf16(sb[12], sb[13]), b7 = cvt_pk_bf16(sb[14], sb[15]);
    asm volatile("v_permlane32_swap_b32 %0, %1" : "+v"(a0), "+v"(a2));
    asm volatile("v_permlane32_swap_b32 %0, %1" : "+v"(a1), "+v"(a3));
    asm volatile("v_permlane32_swap_b32 %0, %1" : "+v"(a4), "+v"(a6));
    asm volatile("v_permlane32_swap_b32 %0, %1" : "+v"(a5), "+v"(a7));
    asm volatile("v_permlane32_swap_b32 %0, %1" : "+v"(b0), "+v"(b2));
    asm volatile("v_permlane32_swap_b32 %0, %1" : "+v"(b1), "+v"(b3));
    asm volatile("v_permlane32_swap_b32 %0, %1" : "+v"(b4), "+v"(b6));
    asm volatile("v_permlane32_swap_b32 %0, %1" : "+v"(b5), "+v"(b7));
    union { unsigned int u[4]; short8 s8; } p0, p1, p2, p3;
    p0.u[0] = a0; p0.u[1] = a1; p0.u[2] = a2; p0.u[3] = a3;
    p1.u[0] = a4; p1.u[1] = a5; p1.u[2] = a6; p1.u[3] = a7;
    p2.u[0] = b0; p2.u[1] = b1; p2.u[2] = b2; p2.u[3] = b3;
    p3.u[0] = b4; p3.u[1] = b5; p3.u[2] = b6; p3.u[3] = b7;
    acc = __builtin_amdgcn_mfma_f32_32x32x16_bf16(p0.s8, V00, acc, 0, 0, 0);
    acc = __builtin_amdgcn_mfma_f32_32x32x16_bf16(p1.s8, V01, acc, 0, 0, 0);
    acc = __builtin_amdgcn_mfma_f32_32x32x16_bf16(p2.s8, V10, acc, 0, 0, 0);
    acc = __builtin_amdgcn_mfma_f32_32x32x16_bf16(p3.s8, V11, acc, 0, 0, 0);
}

// ---------------- zero-LDS flash attention with register prefetch -----------
// grid (N/128, B*H), 256 thr (4 waves x 32 q). 64-key iters; next-iter K/V
// fragments loaded into registers before current compute (T14).
__global__ __launch_bounds__(256) void attn_mfma4(
    const ushort_t* __restrict__ Qb, const ushort_t* __restrict__ Kb,
    const ushort_t* __restrict__ Vt, ushort_t* __restrict__ o)
{
    int bh = blockIdx.y;
    int tid = threadIdx.x;
    int wid = tid >> 6, lane = tid & 63;
    int lq = lane & 31;          // q-col of S^T; also d-col of O
    int half = lane >> 5;
    int qbase = (blockIdx.x << 7) + wid * 32;

    const ushort_t* Qp = Qb + (long)bh * N_ * DH_;
    const ushort_t* kp = Kb + (long)bh * N_ * DH_ + lq * DH_ + half * 8;
    const ushort_t* vp = Vt + (long)bh * DH_ * N_ + (long)lq * N_ + half * 8;

    short8 qf0 = *(const short8*)&Qp[(long)(qbase + lq) * DH_ + half * 8];
    short8 qf1 = *(const short8*)&Qp[(long)(qbase + lq) * DH_ + 16 + half * 8];

    f32x16 acc, Z;
    #pragma unroll
    for (int r = 0; r < 16; ++r) { acc[r] = 0.f; Z[r] = 0.f; }
    float m = -1e30f, lsum = 0.f;

    // prologue: fragments for keys 0..63
    short8 k00 = *(const short8*)(kp +  0 * DH_);
    short8 k01 = *(const short8*)(kp +  0 * DH_ + 16);
    short8 k10 = *(const short8*)(kp + 32 * DH_);
    short8 k11 = *(const short8*)(kp + 32 * DH_ + 16);
    short8 v00 = *(const short8*)(vp +  0);
    short8 v01 = *(const short8*)(vp + 16);
    short8 v10 = *(const short8*)(vp + 32);
    short8 v11 = *(const short8*)(vp + 48);

    for (int it = 0; it < N_ / 64 - 1; ++it) {
        long kn = (long)(it + 1) << 6;
        // prefetch next tile's fragments (issues early, consumed next iter)
        short8 nk00 = *(const short8*)(kp + (kn +  0) * DH_);
        short8 nk01 = *(const short8*)(kp + (kn +  0) * DH_ + 16);
        short8 nk10 = *(const short8*)(kp + (kn + 32) * DH_);
        short8 nk11 = *(const short8*)(kp + (kn + 32) * DH_ + 16);
        short8 nv00 = *(const short8*)(vp + kn);
        short8 nv01 = *(const short8*)(vp + kn + 16);
        short8 nv10 = *(const short8*)(vp + kn + 32);
        short8 nv11 = *(const short8*)(vp + kn + 48);
        attn_tile(k00, k01, k10, k11, v00, v01, v10, v11, qf0, qf1, half, Z, m, lsum, acc);
        k00 = nk00; k01 = nk01; k10 = nk10; k11 = nk11;
        v00 = nv00; v01 = nv01; v10 = nv10; v11 = nv11;
    }
    attn_tile(k00, k01, k10, k11, v00, v01, v10, v11, qf0, qf1, half, Z, m, lsum, acc);

    float invl = 1.f / lsum;
    int b = bh >> 3, h = bh & 7;
    #pragma unroll
    for (int r = 0; r < 16; ++r) {
        int qr = (r & 3) + 8 * (r >> 2) + 4 * half;
        float iv = __shfl(invl, qr, 64);
        long row = (long)b * N_ + qbase + qr;
        o[row * D_ + h * DH_ + lq] = f2bf(acc[r] * iv);
    }
}

// ---------------- fused residual add + LayerNorm; writes fp32 h + bf16 hb ----
__global__ __launch_bounds__(256) void add_ln_kernel(
    float* __restrict__ h, const float* __restrict__ r,
    const float* __restrict__ g, const float* __restrict__ be,
    ushort_t* __restrict__ hb)
{
    int row = blockIdx.x * 4 + (threadIdx.x >> 6);
    int lane = threadIdx.x & 63;
    long off = (long)row * D_ + (lane << 2);
    float4 x = *(float4*)&h[off];
    float4 rr = *(const float4*)&r[off];
    x.x += rr.x; x.y += rr.y; x.z += rr.z; x.w += rr.w;
    float s = x.x + x.y + x.z + x.w;
    #pragma unroll
    for (int k = 1; k < 64; k <<= 1) s += __shfl_xor(s, k, 64);
    float mean = s * (1.f / 256.f);
    float dx = x.x - mean, dy = x.y - mean, dz = x.z - mean, dw = x.w - mean;
    float sq = dx * dx + dy * dy + dz * dz + dw * dw;
    #pragma unroll
    for (int k = 1; k < 64; k <<= 1) sq += __shfl_xor(sq, k, 64);
    float rstd = rsqrtf(sq * (1.f / 256.f) + 1e-5f);
    float4 gv = *(const float4*)&g[lane << 2];
    float4 bv = *(const float4*)&be[lane << 2];
    float4 o;
    o.x = dx * rstd * gv.x + bv.x;
    o.y = dy * rstd * gv.y + bv.y;
    o.z = dz * rstd * gv.z + bv.z;
    o.w = dw * rstd * gv.w + bv.w;
    *(float4*)&h[off] = o;
    ushortx4 ob;
    ob[0] = f2bf(o.x); ob[1] = f2bf(o.y); ob[2] = f2bf(o.z); ob[3] = f2bf(o.w);
    *(ushortx4*)&hb[off] = ob;
}

extern "C" void kernel_launch(void* const* d_in, const int* in_sizes, int n_in,
                              void* d_out, int out_size, void* d_ws, size_t ws_size,
                              hipStream_t stream) {
    const float* h_in    = (const float*)d_in[0];
    const float* pos     = (const float*)d_in[1];
    const float* proj_w  = (const float*)d_in[2];
    const float* proj_b  = (const float*)d_in[3];
    const float* qkv_w   = (const float*)d_in[4];
    const float* out_w   = (const float*)d_in[5];
    const float* out_b   = (const float*)d_in[6];
    const float* O_w     = (const float*)d_in[7];
    const float* O_b     = (const float*)d_in[8];
    const float* ffn1_w  = (const float*)d_in[9];
    const float* ffn1_b  = (const float*)d_in[10];
    const float* ffn2_w  = (const float*)d_in[11];
    const float* ffn2_b  = (const float*)d_in[12];
    const float* ln1_g   = (const float*)d_in[13];
    const float* ln1_b   = (const float*)d_in[14];
    const float* ln2_g   = (const float*)d_in[15];
    const float* ln2_b   = (const float*)d_in[16];
    const float* final_w = (const float*)d_in[17];
    float* out = (float*)d_out;

    float* ws   = (float*)d_ws;
    float* h    = ws;                    // 2,097,152 f
    float* hb_f = h + 2097152;           // 1,048,576 f (bf16 h)
    float* tab  = hb_f + 1048576;        //   262,144 f
    float* WT_f = tab + 262144;          // 1,212,416 f (bf16 weights^T)
    float* R    = WT_f + 1212416;        // 6,291,456 f (qkv fp32, later temps)
    float* QKV  = R + 6291456;           // 3,145,728 f (Qb,Kb,Vt bf16)
    float* tf   = QKV + 3145728;         // 2,097,152 f (W'/b' folds)

    ushort_t* hb  = (ushort_t*)hb_f;
    ushort_t* WT  = (ushort_t*)WT_f;
    float*    qkvf = R;
    ushort_t* aob = (ushort_t*)R;                    // attn out (qkv dead after prep)
    ushort_t* fb  = (ushort_t*)(R + 2097152);        // ffn1 out bf16 (8192x512)
    float*    tf32 = R + 4194304;                    // fp32 GEMM out (8192x256)
    ushort_t* Qb  = (ushort_t*)QKV;
    ushort_t* Kb  = Qb + 2097152;
    ushort_t* Vtg = Kb + 2097152;
    ushort_t* WTp = (ushort_t*)tf;                   // 4 x 65536 bf16
    float*    bp  = tf + 131072;                     // 4 x 256 f32

    const long qkvT_off  = 0;
    const long ffn1T_off = 1310720;
    const long ffn2T_off = 1835008;
    const long finT_off  = 2359296;

    const long M = (long)B_ * N_;    // 8192 rows

    wprep_kernel<<<592, 256, 0, stream>>>(qkv_w, out_w, O_w, ffn1_w, ffn2_w, final_w, WT);
    wfold_kernel<<<64, 256, 0, stream>>>(out_w, O_w, WTp);
    bfold_kernel<<<32, 256, 0, stream>>>(out_b, O_w, O_b, bp);
    proj_kernel<<<(M * 64) / 256, 256, 0, stream>>>(h_in, proj_w, proj_b, h, hb);
    rope_table_kernel<<<(B_ * N_) / 256, 256, 0, stream>>>(pos, tab);

    for (int l = 0; l < L_; ++l) {
        // qkv = hb @ qkv_w[l] -> fp32 qkvf   (N=768, K=256)
        gemm_mfma2<<<dim3(768 / 64, M / 128), 256, 0, stream>>>(
            hb, WT + qkvT_off + (long)l * 196608, nullptr, qkvf, 768, 256, 0);
        // merged RoPE + V-transpose -> Qb, Kb, Vtg
        prep_qkv<<<dim3(N_ / 64, B_ * H_), 256, 0, stream>>>(qkvf, tab, Qb, Kb, Vtg);
        // flash attention -> aob (bf16)
        attn_mfma4<<<dim3(N_ / 128, B_ * H_), 256, 0, stream>>>(Qb, Kb, Vtg, aob);
        // aob @ W'(out@O) + b' -> tf32 (fp32)  (N=256, K=256)
        gemm_mfma2<<<dim3(256 / 64, M / 128), 256, 0, stream>>>(
            aob, WTp + (long)l * 65536, bp + (long)l * 256, tf32, 256, 256, 1);
        // h = LN(h + tf32) -> h, hb
        add_ln_kernel<<<M / 4, 256, 0, stream>>>(
            h, tf32, ln1_g + (long)l * D_, ln1_b + (long)l * D_, hb);
        // ffn1: relu(hb @ ffn1_w + b) -> fb (bf16)  (N=512, K=256)
        gemm_mfma2<<<dim3(512 / 64, M / 128), 256, 0, stream>>>(
            hb, WT + ffn1T_off + (long)l * 131072, ffn1_b + (long)l * 2 * D_, fb, 512, 256, 1 | 2 | 4);
        // ffn2: fb @ ffn2_w + b -> tf32 (fp32)  (N=256, K=512)
        gemm_mfma2<<<dim3(256 / 64, M / 128), 256, 0, stream>>>(
            fb, WT + ffn2T_off + (long)l * 131072, ffn2_b + (long)l * D_, tf32, 256, 512, 1);
        // h = LN(h + tf32) -> h, hb
        add_ln_kernel<<<M / 4, 256, 0, stream>>>(
            h, tf32, ln2_g + (long)l * D_, ln2_b + (long)l * D_, hb);
    }
    // final: hb @ final_w -> out (fp32, no bias)
    gemm_mfma2<<<dim3(256 / 64, M / 128), 256, 0, stream>>>(
        hb, WT + finT_off, nullptr, out, 256, 256, 0);
}